// Round 17
// baseline (1194.484 us; speedup 1.0000x reference)
//
#include <hip/hip_runtime.h>
#include <cstdint>

#define N_NODES 50000
#define N_EDGES 800000
#define N_GRAPHS 1024
#define NODE_IN 128
#define HID 300
#define DEPTH 5
#define READOUT 1024
#define PSTR 320   // plane row stride (elements): 640B rows, zero-padded cols 300..319

typedef float f32x4 __attribute__((ext_vector_type(4)));
typedef short bf16x8 __attribute__((ext_vector_type(8)));
typedef unsigned short us8 __attribute__((ext_vector_type(8)));

__device__ inline unsigned short f2bf(float v) {
    unsigned u = __float_as_uint(v);
    unsigned r = u + 0x7FFFu + ((u >> 16) & 1u);
    return (unsigned short)(r >> 16);
}
__device__ inline float bf2f(unsigned short h) {
    return __uint_as_float((unsigned)h << 16);
}
__device__ inline float bflo(unsigned u) { return __uint_as_float(u << 16); }
__device__ inline float bfhi(unsigned u) { return __uint_as_float(u & 0xFFFF0000u); }
__device__ inline unsigned packbf(float a, float b) {
    return (unsigned)f2bf(a) | ((unsigned)f2bf(b) << 16);
}

// ---------------------------------------------------------------- CSR build (merged)
__global__ void hist2(const int* __restrict__ dst, int* __restrict__ cnt,
                      const int* __restrict__ batch, int* __restrict__ gcnt) {
    int i = blockIdx.x * blockDim.x + threadIdx.x;
    if (i < N_EDGES) atomicAdd(&cnt[dst[i]], 1);
    else if (i < N_EDGES + N_NODES) atomicAdd(&gcnt[batch[i - N_EDGES]], 1);
}

__global__ __launch_bounds__(256)
void scan_block2(const int* __restrict__ cnt, int* __restrict__ offs, int* __restrict__ bsum,
                 const int* __restrict__ gcnt, int* __restrict__ goffs, int* __restrict__ gsum,
                 int nbn) {
    __shared__ int buf[256];
    int b = blockIdx.x;
    const int* in; int* out; int* bs; int n; int bi;
    if (b < nbn) { in = cnt; out = offs; bs = bsum; n = N_NODES; bi = b; }
    else { in = gcnt; out = goffs; bs = gsum; n = N_GRAPHS; bi = b - nbn; }
    int i = bi * 256 + (int)threadIdx.x;
    int v = (i < n) ? in[i] : 0;
    buf[threadIdx.x] = v;
    __syncthreads();
    for (int off = 1; off < 256; off <<= 1) {
        int t = ((int)threadIdx.x >= off) ? buf[threadIdx.x - off] : 0;
        __syncthreads();
        buf[threadIdx.x] += t;
        __syncthreads();
    }
    if (i < n) out[i] = buf[threadIdx.x] - v;
    if (threadIdx.x == 255) bs[bi] = buf[255];
}

__global__ __launch_bounds__(256)
void scan_base2(const int* __restrict__ bsum, int* __restrict__ bbase, int nbn, int* __restrict__ tot_n,
                const int* __restrict__ gsum, int* __restrict__ gbase, int nbg, int* __restrict__ tot_g) {
    __shared__ int buf[256];
    const int* bs; int* bb; int nb; int* tot;
    if (blockIdx.x == 0) { bs = bsum; bb = bbase; nb = nbn; tot = tot_n; }
    else { bs = gsum; bb = gbase; nb = nbg; tot = tot_g; }
    int v = ((int)threadIdx.x < nb) ? bs[threadIdx.x] : 0;
    buf[threadIdx.x] = v;
    __syncthreads();
    for (int off = 1; off < 256; off <<= 1) {
        int t = ((int)threadIdx.x >= off) ? buf[threadIdx.x - off] : 0;
        __syncthreads();
        buf[threadIdx.x] += t;
        __syncthreads();
    }
    if ((int)threadIdx.x < nb) bb[threadIdx.x] = buf[threadIdx.x] - v;
    if (threadIdx.x == 255) *tot = buf[255];
}

__global__ void scan_add2(int* __restrict__ offs, const int* __restrict__ bbase,
                          int* __restrict__ cursor,
                          int* __restrict__ goffs, const int* __restrict__ gbase, int nbn) {
    int b = blockIdx.x;
    if (b < nbn) {
        int i = b * 256 + (int)threadIdx.x;
        if (i < N_NODES) {
            int o = offs[i] + bbase[b];
            offs[i] = o;
            cursor[i] = o;
        }
    } else {
        int bi = b - nbn;
        int i = bi * 256 + (int)threadIdx.x;
        if (i < N_GRAPHS) goffs[i] += gbase[bi];
    }
}

__global__ void scatter_kernel(const int* __restrict__ src, const int* __restrict__ dst,
                               int* __restrict__ cursor, int* __restrict__ csr, int n) {
    int i = blockIdx.x * blockDim.x + threadIdx.x;
    if (i < n) {
        int p = atomicAdd(&cursor[dst[i]], 1);
        csr[p] = src[i];
    }
}

// ---------------------------------------------------------------- aggregation (XCD-sliced)
// slice = blockIdx & 7 -> lands on XCD (slice) via round-robin dispatch; each XCD's
// working set = 50000 x 80B = 4MB = its L2. 10-lane groups own one node's 40-col slice.
#define NPB 24   // nodes per block (4 waves x 6 nodes)
__global__ __launch_bounds__(256)
void aggregate_sliced(const unsigned short* __restrict__ h, const int* __restrict__ offs,
                      const int* __restrict__ csr, unsigned short* __restrict__ out) {
    int slice = blockIdx.x & 7;
    int nb = blockIdx.x >> 3;
    int wave = threadIdx.x >> 6, lane = threadIdx.x & 63;
    int g = lane / 10, e = lane - g * 10;
    if (g >= 6) return;                       // no barriers below: safe
    int node = nb * NPB + wave * 6 + g;
    if (node >= N_NODES) return;
    size_t co = (size_t)slice * 40 + e * 4;   // element offset of this lane's uint2
    uint2 v = *(const uint2*)(h + (size_t)node * PSTR + co);
    float a0 = bflo(v.x), a1 = bfhi(v.x), a2 = bflo(v.y), a3 = bfhi(v.y);
    int s = offs[node], en = offs[node + 1];
    int k = s;
    for (; k + 3 < en; k += 4) {
        int i0 = csr[k], i1 = csr[k + 1], i2 = csr[k + 2], i3 = csr[k + 3];
        uint2 v0 = *(const uint2*)(h + (size_t)i0 * PSTR + co);
        uint2 v1 = *(const uint2*)(h + (size_t)i1 * PSTR + co);
        uint2 v2 = *(const uint2*)(h + (size_t)i2 * PSTR + co);
        uint2 v3 = *(const uint2*)(h + (size_t)i3 * PSTR + co);
        a0 += bflo(v0.x) + bflo(v1.x) + bflo(v2.x) + bflo(v3.x);
        a1 += bfhi(v0.x) + bfhi(v1.x) + bfhi(v2.x) + bfhi(v3.x);
        a2 += bflo(v0.y) + bflo(v1.y) + bflo(v2.y) + bflo(v3.y);
        a3 += bfhi(v0.y) + bfhi(v1.y) + bfhi(v2.y) + bfhi(v3.y);
    }
    for (; k < en; ++k) {
        uint2 vv = *(const uint2*)(h + (size_t)csr[k] * PSTR + co);
        a0 += bflo(vv.x); a1 += bfhi(vv.x);
        a2 += bflo(vv.y); a3 += bfhi(vv.y);
    }
    uint2 w; w.x = packbf(a0, a1); w.y = packbf(a2, a3);
    *(uint2*)(out + (size_t)node * PSTR + co) = w;
}

// ---------------------------------------------------------------- weight pre-split
// z<10: hidden W -> SINGLE bf16 plane [320][320] (transposed)
// z==10: W_sp -> hi/lo [1280][320]; z==11: Wproj -> hi/lo [320][128]
__global__ __launch_bounds__(256)
void split_all(const float* __restrict__ W1, const float* __restrict__ W2,
               const float* __restrict__ Wsp, const float* __restrict__ Wproj,
               unsigned short* __restrict__ w1H, unsigned short* __restrict__ w2H,
               unsigned short* __restrict__ spH, unsigned short* __restrict__ spL,
               unsigned short* __restrict__ pjH, unsigned short* __restrict__ pjL) {
    __shared__ float tile[32][33];
    const int LAYER_SZ = 320 * 320;
    int z = blockIdx.z;
    const float* W; unsigned short* H = nullptr; unsigned short* L = nullptr;
    int K, N, KP;
    if (z < 10) {
        if (blockIdx.x >= 10) return;
        int l = z % 5;
        W = (z < 5 ? W1 : W2) + (size_t)l * HID * HID;
        H = (z < 5 ? w1H : w2H) + (size_t)l * LAYER_SZ;
        K = HID; N = HID; KP = 320;
    } else if (z == 10) {
        W = Wsp; H = spH; L = spL; K = HID; N = READOUT; KP = 320;
    } else {
        if (blockIdx.x >= 10 || blockIdx.y >= 4) return;
        W = Wproj; H = pjH; L = pjL; K = NODE_IN; N = HID; KP = 128;
    }
    int n0 = blockIdx.x * 32, k0 = blockIdx.y * 32;
    int tx = threadIdx.x & 31, ty = threadIdx.x >> 5;
#pragma unroll
    for (int r = 0; r < 4; ++r) {
        int k = k0 + ty + r * 8, n = n0 + tx;
        tile[ty + r * 8][tx] = (k < K && n < N) ? W[(size_t)k * N + n] : 0.f;
    }
    __syncthreads();
#pragma unroll
    for (int r = 0; r < 4; ++r) {
        int n = n0 + ty + r * 8, k = k0 + tx;
        float v = tile[tx][ty + r * 8];
        unsigned short hb = f2bf(v);
        H[(size_t)n * KP + k] = hb;
        if (L) L[(size_t)n * KP + k] = f2bf(v - bf2f(hb));
    }
}

#define BSWZ(r, c) ((c) ^ (((r) >> 1) & 3))

// ---------------------------------------------------------------- fused GIN MLP (dbuf Bs, 1 barrier/step)
// out = act2( relu( A @ W1 + b1 ) @ W2 + b2 )  -> bf16 plane
// 391 blocks x 128 rows, 512 thr (8 waves, 2M x 4N, wave tile 64x80, acc[4][5]).
// LDS: At 80KB (XOR-swizzled) + Bs 2x20KB double-buffer = 120KB.
__global__ __launch_bounds__(512)
void gin_mlp(const unsigned short* __restrict__ Ap, int M,
             const unsigned short* __restrict__ B1, const float* __restrict__ b1,
             const unsigned short* __restrict__ B2, const float* __restrict__ b2,
             unsigned short* __restrict__ Op, int act2) {
    __shared__ __align__(16) unsigned short At[128 * 320];   // 80 KB
    __shared__ __align__(16) unsigned short Bs[2][10240];    // 40 KB dbuf

    const int tid = threadIdx.x;
    const int bm = blockIdx.x * 128;
    const int wid = tid >> 6, lane = tid & 63;
    const int wm = wid >> 2, wn = wid & 3;
    const int lr = lane & 15, lk = lane >> 4;

    float b1v[5], b2v[5];
#pragma unroll
    for (int n = 0; n < 5; ++n) {
        int col = wn * 80 + n * 16 + lr;
        b1v[n] = (col < HID) ? b1[col] : 0.f;
        b2v[n] = (col < HID) ? b2[col] : 0.f;
    }

    // B chunk meta: 1280 chunks / 512 thr -> 3 iters (last partial)
    size_t bofs[3]; int bldso[3]; bool bval[3];
#pragma unroll
    for (int i = 0; i < 3; ++i) {
        int q = i * 512 + tid;
        bval[i] = q < 1280;
        int r = (q < 1280 ? q : 0) >> 2, c = q & 3;
        bofs[i] = (size_t)r * 320 + c * 8;
        bldso[i] = r * 32 + BSWZ(r, c) * 8;
    }

    us8 vB[3];
    auto LOADB = [&](const unsigned short* B, int t) {
        int k0 = t * 32;
#pragma unroll
        for (int i = 0; i < 3; ++i)
            if (bval[i]) vB[i] = *(const us8*)&B[bofs[i] + k0];
    };
    auto WRITEB = [&](int b) {
#pragma unroll
        for (int i = 0; i < 3; ++i)
            if (bval[i]) *(us8*)&Bs[b][bldso[i]] = vB[i];
    };

    LOADB(B1, 0);   // in flight during A staging

    // ---- stage A (128 x 320, once) ----
#pragma unroll
    for (int i = 0; i < 10; ++i) {
        int g = i * 512 + tid;        // 0..5119
        int row = g / 40, c = g - row * 40;
        int grow = bm + row; if (grow >= M) grow = M - 1;
        us8 v = *(const us8*)&Ap[(size_t)grow * PSTR + c * 8];
        *(us8*)&At[row * 320 + (c ^ (row & 7)) * 8] = v;
    }
    WRITEB(0);            // B1 step 0 -> Bs[0]
    LOADB(B1, 1);
    __syncthreads();      // At + Bs[0] visible

    f32x4 acc[4][5];

    // one barrier per step; compute(t) reads Bs[t&1] while Bs[(t+1)&1] fills
    auto RUN = [&](const unsigned short* B, const unsigned short* Bnext) {
        for (int t = 0; t < 10; ++t) {
            bf16x8 aS[4];
#pragma unroll
            for (int m = 0; m < 4; ++m) {
                int row = wm * 64 + m * 16 + lr;
                int c = t * 4 + lk;
                aS[m] = *(const bf16x8*)&At[row * 320 + (c ^ (row & 7)) * 8];
            }
#pragma unroll
            for (int n = 0; n < 5; ++n) {
                int rb = wn * 80 + n * 16 + lr;
                bf16x8 bh = *(const bf16x8*)&Bs[t & 1][rb * 32 + BSWZ(rb, lk) * 8];
#pragma unroll
                for (int m = 0; m < 4; ++m)
                    acc[m][n] = __builtin_amdgcn_mfma_f32_16x16x32_bf16(aS[m], bh, acc[m][n], 0, 0, 0);
            }
            if (t < 9) {
                WRITEB((t + 1) & 1);                 // vB holds step t+1
                if (t < 8) LOADB(B, t + 2);
                else if (Bnext) LOADB(Bnext, 0);     // prefetch next GEMM's step 0
            }
            __syncthreads();
        }
    };

    // ---- GEMM1 ----
#pragma unroll
    for (int m = 0; m < 4; ++m)
#pragma unroll
        for (int n = 0; n < 5; ++n) acc[m][n] = (f32x4)0.f;
    RUN(B1, B2);
    // after GEMM1: vB holds B2 step 0; final barrier done (At reads drained)

    // ---- T = relu(acc + b1) -> At ; stage B2 step 0 -> Bs[0] ----
#pragma unroll
    for (int n = 0; n < 5; ++n) {
        int col = wn * 80 + n * 16 + lr;
        int cc = col >> 3, cp = col & 7;
        float bv = b1v[n];
        bool vc = col < HID;
#pragma unroll
        for (int m = 0; m < 4; ++m) {
#pragma unroll
            for (int p = 0; p < 4; ++p) {
                int row = wm * 64 + m * 16 + lk * 4 + p;
                float v = vc ? fmaxf(acc[m][n][p] + bv, 0.f) : 0.f;
                At[row * 320 + ((cc ^ (row & 7)) * 8) + cp] = f2bf(v);
            }
        }
    }
    WRITEB(0);            // Bs[0] last read at t=8 (fenced by t=9 barrier)
    LOADB(B2, 1);
    __syncthreads();      // T + Bs[0] visible

    // ---- GEMM2 ----
#pragma unroll
    for (int m = 0; m < 4; ++m)
#pragma unroll
        for (int n = 0; n < 5; ++n) acc[m][n] = (f32x4)0.f;
    RUN(B2, nullptr);

    // ---- epilogue: act2(acc + b2) -> At -> coalesced stores ----
#pragma unroll
    for (int n = 0; n < 5; ++n) {
        int col = wn * 80 + n * 16 + lr;
        int cc = col >> 3, cp = col & 7;
        float bv = b2v[n];
        bool vc = col < HID;
#pragma unroll
        for (int m = 0; m < 4; ++m) {
#pragma unroll
            for (int p = 0; p < 4; ++p) {
                int row = wm * 64 + m * 16 + lk * 4 + p;
                float v = vc ? (acc[m][n][p] + bv) : 0.f;
                if (act2) v = fmaxf(v, 0.f);
                At[row * 320 + ((cc ^ (row & 7)) * 8) + cp] = f2bf(v);
            }
        }
    }
    __syncthreads();
#pragma unroll
    for (int i = 0; i < 10; ++i) {
        int g = i * 512 + tid;
        int row = g / 40, c = g - row * 40;
        int grow = bm + row;
        if (grow < M)
            *(us8*)&Op[(size_t)grow * PSTR + c * 8] =
                *(const us8*)&At[row * 320 + (c ^ (row & 7)) * 8];
    }
}

// ---------------------------------------------------------------- GEMM: fp32 A, 3-term split
// proj (outPlane=1: bf16 plane out, relu) and readout (outPlane=0: f32 out, prelu)
__global__ __launch_bounds__(256)
void gemm_f32A(const float* __restrict__ A, int lda, int M, int K, int KP,
               const unsigned short* __restrict__ BH, const unsigned short* __restrict__ BL, int KPB,
               const float* __restrict__ bias, int N,
               float* __restrict__ C, int ldc, unsigned short* __restrict__ Op, int outPlane,
               int act, const float* __restrict__ prelu) {
    __shared__ __align__(16) unsigned short AsH[64 * 40];
    __shared__ __align__(16) unsigned short AsL[64 * 40];
    __shared__ __align__(16) unsigned short BsH[320 * 40];
    __shared__ __align__(16) unsigned short BsL[320 * 40];

    const int tid = threadIdx.x;
    const int bm = blockIdx.y * 64;
    const int bn = blockIdx.x * 320;
    const int wid = tid >> 6, lane = tid & 63;
    const int lr = lane & 15, lk = lane >> 4;
    const int ar = tid >> 2, ac = tid & 3;

    f32x4 acc[4][5];
#pragma unroll
    for (int m = 0; m < 4; ++m)
#pragma unroll
        for (int n = 0; n < 5; ++n) acc[m][n] = (f32x4)0.f;

    for (int k0 = 0; k0 < KP; k0 += 32) {
        {
            int gm = bm + ar;
            int k = k0 + ac * 8;
            float v[8];
#pragma unroll
            for (int j = 0; j < 8; ++j) v[j] = 0.f;
            if (gm < M) {
                if (k + 7 < K) {
                    float4 p0 = *(const float4*)&A[(size_t)gm * lda + k];
                    float4 p1 = *(const float4*)&A[(size_t)gm * lda + k + 4];
                    v[0] = p0.x; v[1] = p0.y; v[2] = p0.z; v[3] = p0.w;
                    v[4] = p1.x; v[5] = p1.y; v[6] = p1.z; v[7] = p1.w;
                } else {
#pragma unroll
                    for (int j = 0; j < 8; ++j)
                        if (k + j < K) v[j] = A[(size_t)gm * lda + k + j];
                }
            }
            us8 h, l;
#pragma unroll
            for (int j = 0; j < 8; ++j) {
                unsigned short hb = f2bf(v[j]);
                h[j] = hb;
                l[j] = f2bf(v[j] - bf2f(hb));
            }
            *(us8*)&AsH[ar * 40 + ac * 8] = h;
            *(us8*)&AsL[ar * 40 + ac * 8] = l;
        }
#pragma unroll
        for (int p = 0; p < 5; ++p) {
            int r = ar + p * 64;
            size_t gb = (size_t)(bn + r) * KPB + k0 + ac * 8;
            *(us8*)&BsH[r * 40 + ac * 8] = *(const us8*)&BH[gb];
            *(us8*)&BsL[r * 40 + ac * 8] = *(const us8*)&BL[gb];
        }
        __syncthreads();
        bf16x8 aH[4], aL[4];
#pragma unroll
        for (int m = 0; m < 4; ++m) {
            aH[m] = *(const bf16x8*)&AsH[(m * 16 + lr) * 40 + lk * 8];
            aL[m] = *(const bf16x8*)&AsL[(m * 16 + lr) * 40 + lk * 8];
        }
#pragma unroll
        for (int n = 0; n < 5; ++n) {
            int r = wid * 80 + n * 16 + lr;
            bf16x8 bh = *(const bf16x8*)&BsH[r * 40 + lk * 8];
            bf16x8 bl = *(const bf16x8*)&BsL[r * 40 + lk * 8];
#pragma unroll
            for (int m = 0; m < 4; ++m) {
                acc[m][n] = __builtin_amdgcn_mfma_f32_16x16x32_bf16(aH[m], bh, acc[m][n], 0, 0, 0);
                acc[m][n] = __builtin_amdgcn_mfma_f32_16x16x32_bf16(aH[m], bl, acc[m][n], 0, 0, 0);
                acc[m][n] = __builtin_amdgcn_mfma_f32_16x16x32_bf16(aL[m], bh, acc[m][n], 0, 0, 0);
            }
        }
        __syncthreads();
    }
    float slope = (act == 2) ? prelu[0] : 0.f;
#pragma unroll
    for (int n = 0; n < 5; ++n) {
        int col = bn + wid * 80 + n * 16 + lr;
        bool vc = col < N;
        float bv = vc ? bias[col] : 0.f;
#pragma unroll
        for (int m = 0; m < 4; ++m) {
            int rbase = bm + m * 16 + lk * 4;
#pragma unroll
            for (int p = 0; p < 4; ++p) {
                int row = rbase + p;
                if (row >= M) continue;
                float v = vc ? (acc[m][n][p] + bv) : 0.f;
                if (act == 1) v = fmaxf(v, 0.f);
                else if (act == 2) v = (v >= 0.f) ? v : slope * v;
                if (outPlane) {
                    if (col < PSTR) Op[(size_t)row * PSTR + col] = f2bf(v);
                } else if (vc) {
                    C[(size_t)row * ldc + col] = v;
                }
            }
        }
    }
}

// ---------------------------------------------------------------- segmented pool (2 waves/graph)
__global__ __launch_bounds__(128)
void pool_seg(const unsigned short* __restrict__ h, const int* __restrict__ goffs,
              float* __restrict__ pooled) {
    __shared__ float red[6 * 64];
    int g = blockIdx.x;
    int w = threadIdx.x >> 6, lane = threadIdx.x & 63;
    int s = goffs[g], e = goffs[g + 1];
    float a0 = 0.f, a1 = 0.f, a2 = 0.f, a3 = 0.f, a4 = 0.f, a5 = 0.f;
    for (int node = s + w; node < e; node += 2) {
        const unsigned* r = (const unsigned*)(h + (size_t)node * PSTR);
        uint2 u = *(const uint2*)&r[2 * lane];
        unsigned t = (lane < 32) ? r[128 + lane] : 0u;
        a0 += bflo(u.x); a1 += bfhi(u.x);
        a2 += bflo(u.y); a3 += bfhi(u.y);
        a4 += bflo(t);   a5 += bfhi(t);
    }
    if (w == 1) {
        red[lane] = a0;        red[64 + lane] = a1;
        red[128 + lane] = a2;  red[192 + lane] = a3;
        red[256 + lane] = a4;  red[320 + lane] = a5;
    }
    __syncthreads();
    if (w == 0) {
        a0 += red[lane];        a1 += red[64 + lane];
        a2 += red[128 + lane];  a3 += red[192 + lane];
        a4 += red[256 + lane];  a5 += red[320 + lane];
        float* pr = pooled + (size_t)g * PSTR;
        *(float4*)&pr[4 * lane] = make_float4(a0, a1, a2, a3);
        if (lane < 32) *(float2*)&pr[256 + 2 * lane] = make_float2(a4, a5);
    }
}

// ---------------------------------------------------------------- launch
extern "C" void kernel_launch(void* const* d_in, const int* in_sizes, int n_in,
                              void* d_out, int out_size, void* d_ws, size_t ws_size,
                              hipStream_t stream) {
    const float* x      = (const float*)d_in[0];
    const int*   eidx   = (const int*)d_in[1];
    const int*   batch  = (const int*)d_in[2];
    const float* W_proj = (const float*)d_in[3];
    const float* b_proj = (const float*)d_in[4];
    const float* W1     = (const float*)d_in[5];
    const float* b1     = (const float*)d_in[6];
    const float* W2     = (const float*)d_in[7];
    const float* b2     = (const float*)d_in[8];
    const float* W_sp   = (const float*)d_in[9];
    const float* b_sp   = (const float*)d_in[10];
    const float* prelu  = (const float*)d_in[11];

    const int* src = eidx;
    const int* dst = eidx + N_EDGES;

    const size_t PLANE = (size_t)N_NODES * PSTR + 64;
    const int LAYER_SZ = 320 * 320;
    const int SP_SZ  = 1280 * 320;
    const int PJ_SZ  = 320 * 128;
    const int NB  = (N_NODES + 255) / 256;   // 196
    const int NBG = (N_GRAPHS + 255) / 256;  // 4

    unsigned short* hA  = (unsigned short*)d_ws;       // PLANE
    unsigned short* hB  = hA + PLANE;                  // PLANE
    float* pooled = (float*)(hB + PLANE);
    unsigned short* w1H = (unsigned short*)(pooled + (size_t)N_GRAPHS * PSTR + 16);
    unsigned short* w2H = w1H + 5 * (size_t)LAYER_SZ;
    unsigned short* spH = w2H + 5 * (size_t)LAYER_SZ;
    unsigned short* spL = spH + SP_SZ;
    unsigned short* pjH = spL + SP_SZ;
    unsigned short* pjL = pjH + PJ_SZ;
    int* cnt    = (int*)(((uintptr_t)(pjL + PJ_SZ) + 15) & ~(uintptr_t)15);
    int* gcnt   = cnt + N_NODES;
    int* bsum   = gcnt + N_GRAPHS;
    int* bbase  = bsum + 256;
    int* gsum   = bbase + 256;
    int* gbase  = gsum + 256;
    int* offs   = gbase + 256;
    int* goffs  = offs + N_NODES + 1;
    int* cursor = goffs + N_GRAPHS + 1;
    int* csr    = cursor + N_NODES;
    size_t needed = (size_t)((uintptr_t)(csr + N_EDGES) - (uintptr_t)d_ws);
    if (ws_size < needed) return;

    // ---- weight pre-split (one launch) ----
    split_all<<<dim3(40, 10, 12), 256, 0, stream>>>(W1, W2, W_sp, W_proj,
                                                    w1H, w2H, spH, spL, pjH, pjL);

    // ---- CSR + graph offsets (merged chains) ----
    hipMemsetAsync(cnt, 0, (N_NODES + N_GRAPHS) * sizeof(int), stream);
    hist2<<<(N_EDGES + N_NODES + 255) / 256, 256, 0, stream>>>(dst, cnt, batch, gcnt);
    scan_block2<<<NB + NBG, 256, 0, stream>>>(cnt, offs, bsum, gcnt, goffs, gsum, NB);
    scan_base2<<<2, 256, 0, stream>>>(bsum, bbase, NB, offs + N_NODES,
                                      gsum, gbase, NBG, goffs + N_GRAPHS);
    scan_add2<<<NB + NBG, 256, 0, stream>>>(offs, bbase, cursor, goffs, gbase, NB);
    scatter_kernel<<<(N_EDGES + 255) / 256, 256, 0, stream>>>(src, dst, cursor, csr, N_EDGES);

    // ---- projection: h0 = relu(x @ W_proj + b) -> hA (bf16 plane) ----
    gemm_f32A<<<dim3(1, (N_NODES + 63) / 64), 256, 0, stream>>>(
        x, NODE_IN, N_NODES, NODE_IN, 128, pjH, pjL, 128,
        b_proj, HID, nullptr, 0, hA, 1, 1, nullptr);

    // ---- GIN layers: agg (XCD-sliced) + fused MLP (dbuf, 1 barrier/step) ----
    const int GBM  = (N_NODES + 127) / 128;            // 391
    const int GAGG = ((N_NODES + NPB - 1) / NPB) * 8;  // 2084 * 8 = 16672
    unsigned short* cur = hA;
    unsigned short* agp = hB;
    for (int i = 0; i < DEPTH; ++i) {
        aggregate_sliced<<<GAGG, 256, 0, stream>>>(cur, offs, csr, agp);
        gin_mlp<<<GBM, 512, 0, stream>>>(
            agp, N_NODES,
            w1H + (size_t)i * LAYER_SZ, b1 + (size_t)i * HID,
            w2H + (size_t)i * LAYER_SZ, b2 + (size_t)i * HID,
            cur, (i < DEPTH - 1) ? 1 : 0);
    }

    // ---- segmented pool (batch sorted) ----
    pool_seg<<<N_GRAPHS, 128, 0, stream>>>(cur, goffs, pooled);

    // ---- readout: prelu(pooled @ W_sp + b_sp) ----
    gemm_f32A<<<dim3(4, (N_GRAPHS + 63) / 64), 256, 0, stream>>>(
        pooled, PSTR, N_GRAPHS, HID, 320, spH, spL, 320,
        b_sp, READOUT, (float*)d_out, READOUT, nullptr, 0, 2, prelu);
}

// Round 18
// 859.783 us; speedup vs baseline: 1.3893x; 1.3893x over previous
//
#include <hip/hip_runtime.h>
#include <cstdint>

#define N_NODES 50000
#define N_EDGES 800000
#define N_GRAPHS 1024
#define NODE_IN 128
#define HID 300
#define DEPTH 5
#define READOUT 1024
#define PSTR 320   // plane row stride (elements): 640B rows, zero-padded cols 300..319

typedef float f32x4 __attribute__((ext_vector_type(4)));
typedef short bf16x8 __attribute__((ext_vector_type(8)));
typedef unsigned short us8 __attribute__((ext_vector_type(8)));

__device__ inline unsigned short f2bf(float v) {
    unsigned u = __float_as_uint(v);
    unsigned r = u + 0x7FFFu + ((u >> 16) & 1u);
    return (unsigned short)(r >> 16);
}
__device__ inline float bf2f(unsigned short h) {
    return __uint_as_float((unsigned)h << 16);
}
__device__ inline float bflo(unsigned u) { return __uint_as_float(u << 16); }
__device__ inline float bfhi(unsigned u) { return __uint_as_float(u & 0xFFFF0000u); }
__device__ inline unsigned packbf(float a, float b) {
    return (unsigned)f2bf(a) | ((unsigned)f2bf(b) << 16);
}

// ---------------------------------------------------------------- CSR build (merged)
__global__ void hist2(const int* __restrict__ dst, int* __restrict__ cnt,
                      const int* __restrict__ batch, int* __restrict__ gcnt) {
    int i = blockIdx.x * blockDim.x + threadIdx.x;
    if (i < N_EDGES) atomicAdd(&cnt[dst[i]], 1);
    else if (i < N_EDGES + N_NODES) atomicAdd(&gcnt[batch[i - N_EDGES]], 1);
}

__global__ __launch_bounds__(256)
void scan_block2(const int* __restrict__ cnt, int* __restrict__ offs, int* __restrict__ bsum,
                 const int* __restrict__ gcnt, int* __restrict__ goffs, int* __restrict__ gsum,
                 int nbn) {
    __shared__ int buf[256];
    int b = blockIdx.x;
    const int* in; int* out; int* bs; int n; int bi;
    if (b < nbn) { in = cnt; out = offs; bs = bsum; n = N_NODES; bi = b; }
    else { in = gcnt; out = goffs; bs = gsum; n = N_GRAPHS; bi = b - nbn; }
    int i = bi * 256 + (int)threadIdx.x;
    int v = (i < n) ? in[i] : 0;
    buf[threadIdx.x] = v;
    __syncthreads();
    for (int off = 1; off < 256; off <<= 1) {
        int t = ((int)threadIdx.x >= off) ? buf[threadIdx.x - off] : 0;
        __syncthreads();
        buf[threadIdx.x] += t;
        __syncthreads();
    }
    if (i < n) out[i] = buf[threadIdx.x] - v;
    if (threadIdx.x == 255) bs[bi] = buf[255];
}

__global__ __launch_bounds__(256)
void scan_base2(const int* __restrict__ bsum, int* __restrict__ bbase, int nbn, int* __restrict__ tot_n,
                const int* __restrict__ gsum, int* __restrict__ gbase, int nbg, int* __restrict__ tot_g) {
    __shared__ int buf[256];
    const int* bs; int* bb; int nb; int* tot;
    if (blockIdx.x == 0) { bs = bsum; bb = bbase; nb = nbn; tot = tot_n; }
    else { bs = gsum; bb = gbase; nb = nbg; tot = tot_g; }
    int v = ((int)threadIdx.x < nb) ? bs[threadIdx.x] : 0;
    buf[threadIdx.x] = v;
    __syncthreads();
    for (int off = 1; off < 256; off <<= 1) {
        int t = ((int)threadIdx.x >= off) ? buf[threadIdx.x - off] : 0;
        __syncthreads();
        buf[threadIdx.x] += t;
        __syncthreads();
    }
    if ((int)threadIdx.x < nb) bb[threadIdx.x] = buf[threadIdx.x] - v;
    if (threadIdx.x == 255) *tot = buf[255];
}

__global__ void scan_add2(int* __restrict__ offs, const int* __restrict__ bbase,
                          int* __restrict__ cursor,
                          int* __restrict__ goffs, const int* __restrict__ gbase, int nbn) {
    int b = blockIdx.x;
    if (b < nbn) {
        int i = b * 256 + (int)threadIdx.x;
        if (i < N_NODES) {
            int o = offs[i] + bbase[b];
            offs[i] = o;
            cursor[i] = o;
        }
    } else {
        int bi = b - nbn;
        int i = bi * 256 + (int)threadIdx.x;
        if (i < N_GRAPHS) goffs[i] += gbase[bi];
    }
}

__global__ void scatter_kernel(const int* __restrict__ src, const int* __restrict__ dst,
                               int* __restrict__ cursor, int* __restrict__ csr, int n) {
    int i = blockIdx.x * blockDim.x + threadIdx.x;
    if (i < n) {
        int p = atomicAdd(&cursor[dst[i]], 1);
        csr[p] = src[i];
    }
}

// ---------------------------------------------------------------- aggregation (bf16 planes)
__global__ __launch_bounds__(256)
void aggregate_bf16(const unsigned short* __restrict__ h, const int* __restrict__ offs,
                    const int* __restrict__ csr, unsigned short* __restrict__ out) {
    int wave = (int)((blockIdx.x * blockDim.x + threadIdx.x) >> 6);
    int lane = threadIdx.x & 63;
    if (wave >= N_NODES) return;
    bool act = lane < 40;
    size_t lo = (size_t)lane * 8;
    float a0 = 0.f, a1 = 0.f, a2 = 0.f, a3 = 0.f, a4 = 0.f, a5 = 0.f, a6 = 0.f, a7 = 0.f;
    if (act) {
        uint4 v = *(const uint4*)(h + (size_t)wave * PSTR + lo);
        a0 = bflo(v.x); a1 = bfhi(v.x); a2 = bflo(v.y); a3 = bfhi(v.y);
        a4 = bflo(v.z); a5 = bfhi(v.z); a6 = bflo(v.w); a7 = bfhi(v.w);
    }
    int s = offs[wave], e = offs[wave + 1];
    int k = s;
    for (; k + 3 < e; k += 4) {
        int i0 = csr[k], i1 = csr[k + 1], i2 = csr[k + 2], i3 = csr[k + 3];
        if (act) {
            uint4 v0 = *(const uint4*)(h + (size_t)i0 * PSTR + lo);
            uint4 v1 = *(const uint4*)(h + (size_t)i1 * PSTR + lo);
            uint4 v2 = *(const uint4*)(h + (size_t)i2 * PSTR + lo);
            uint4 v3 = *(const uint4*)(h + (size_t)i3 * PSTR + lo);
            a0 += bflo(v0.x) + bflo(v1.x) + bflo(v2.x) + bflo(v3.x);
            a1 += bfhi(v0.x) + bfhi(v1.x) + bfhi(v2.x) + bfhi(v3.x);
            a2 += bflo(v0.y) + bflo(v1.y) + bflo(v2.y) + bflo(v3.y);
            a3 += bfhi(v0.y) + bfhi(v1.y) + bfhi(v2.y) + bfhi(v3.y);
            a4 += bflo(v0.z) + bflo(v1.z) + bflo(v2.z) + bflo(v3.z);
            a5 += bfhi(v0.z) + bfhi(v1.z) + bfhi(v2.z) + bfhi(v3.z);
            a6 += bflo(v0.w) + bflo(v1.w) + bflo(v2.w) + bflo(v3.w);
            a7 += bfhi(v0.w) + bfhi(v1.w) + bfhi(v2.w) + bfhi(v3.w);
        }
    }
    for (; k < e; ++k) {
        int i0 = csr[k];
        if (act) {
            uint4 v = *(const uint4*)(h + (size_t)i0 * PSTR + lo);
            a0 += bflo(v.x); a1 += bfhi(v.x); a2 += bflo(v.y); a3 += bfhi(v.y);
            a4 += bflo(v.z); a5 += bfhi(v.z); a6 += bflo(v.w); a7 += bfhi(v.w);
        }
    }
    if (act) {
        uint4 w;
        w.x = packbf(a0, a1); w.y = packbf(a2, a3);
        w.z = packbf(a4, a5); w.w = packbf(a6, a7);
        *(uint4*)(out + (size_t)wave * PSTR + lo) = w;
    }
}

// ---------------------------------------------------------------- weight pre-split
// z<10: hidden W -> SINGLE bf16 plane [320][320] (transposed)
// z==10: W_sp -> hi/lo [1280][320]; z==11: Wproj -> hi/lo [320][128]
__global__ __launch_bounds__(256)
void split_all(const float* __restrict__ W1, const float* __restrict__ W2,
               const float* __restrict__ Wsp, const float* __restrict__ Wproj,
               unsigned short* __restrict__ w1H, unsigned short* __restrict__ w2H,
               unsigned short* __restrict__ spH, unsigned short* __restrict__ spL,
               unsigned short* __restrict__ pjH, unsigned short* __restrict__ pjL) {
    __shared__ float tile[32][33];
    const int LAYER_SZ = 320 * 320;
    int z = blockIdx.z;
    const float* W; unsigned short* H = nullptr; unsigned short* L = nullptr;
    int K, N, KP;
    if (z < 10) {
        if (blockIdx.x >= 10) return;
        int l = z % 5;
        W = (z < 5 ? W1 : W2) + (size_t)l * HID * HID;
        H = (z < 5 ? w1H : w2H) + (size_t)l * LAYER_SZ;
        K = HID; N = HID; KP = 320;
    } else if (z == 10) {
        W = Wsp; H = spH; L = spL; K = HID; N = READOUT; KP = 320;
    } else {
        if (blockIdx.x >= 10 || blockIdx.y >= 4) return;
        W = Wproj; H = pjH; L = pjL; K = NODE_IN; N = HID; KP = 128;
    }
    int n0 = blockIdx.x * 32, k0 = blockIdx.y * 32;
    int tx = threadIdx.x & 31, ty = threadIdx.x >> 5;
#pragma unroll
    for (int r = 0; r < 4; ++r) {
        int k = k0 + ty + r * 8, n = n0 + tx;
        tile[ty + r * 8][tx] = (k < K && n < N) ? W[(size_t)k * N + n] : 0.f;
    }
    __syncthreads();
#pragma unroll
    for (int r = 0; r < 4; ++r) {
        int n = n0 + ty + r * 8, k = k0 + tx;
        float v = tile[tx][ty + r * 8];
        unsigned short hb = f2bf(v);
        H[(size_t)n * KP + k] = hb;
        if (L) L[(size_t)n * KP + k] = f2bf(v - bf2f(hb));
    }
}

#define BSWZ(r, c) ((c) ^ (((r) >> 1) & 3))

// ---------------------------------------------------------------- fused GIN MLP (dbuf Bs, 1 barrier/step)
// out = act2( relu( A @ W1 + b1 ) @ W2 + b2 )  -> bf16 plane
// 391 blocks x 128 rows, 512 thr (8 waves, 2M x 4N, wave tile 64x80, acc[4][5]).
// LDS: At 80KB (XOR-swizzled) + Bs 2x20KB double-buffer = 120KB.
__global__ __launch_bounds__(512)
void gin_mlp(const unsigned short* __restrict__ Ap, int M,
             const unsigned short* __restrict__ B1, const float* __restrict__ b1,
             const unsigned short* __restrict__ B2, const float* __restrict__ b2,
             unsigned short* __restrict__ Op, int act2) {
    __shared__ __align__(16) unsigned short At[128 * 320];   // 80 KB
    __shared__ __align__(16) unsigned short Bs[2][10240];    // 40 KB dbuf

    const int tid = threadIdx.x;
    const int bm = blockIdx.x * 128;
    const int wid = tid >> 6, lane = tid & 63;
    const int wm = wid >> 2, wn = wid & 3;
    const int lr = lane & 15, lk = lane >> 4;

    float b1v[5], b2v[5];
#pragma unroll
    for (int n = 0; n < 5; ++n) {
        int col = wn * 80 + n * 16 + lr;
        b1v[n] = (col < HID) ? b1[col] : 0.f;
        b2v[n] = (col < HID) ? b2[col] : 0.f;
    }

    // B chunk meta: 1280 chunks / 512 thr -> 3 iters (last partial)
    size_t bofs[3]; int bldso[3]; bool bval[3];
#pragma unroll
    for (int i = 0; i < 3; ++i) {
        int q = i * 512 + tid;
        bval[i] = q < 1280;
        int r = (q < 1280 ? q : 0) >> 2, c = q & 3;
        bofs[i] = (size_t)r * 320 + c * 8;
        bldso[i] = r * 32 + BSWZ(r, c) * 8;
    }

    us8 vB[3];
    auto LOADB = [&](const unsigned short* B, int t) {
        int k0 = t * 32;
#pragma unroll
        for (int i = 0; i < 3; ++i)
            if (bval[i]) vB[i] = *(const us8*)&B[bofs[i] + k0];
    };
    auto WRITEB = [&](int b) {
#pragma unroll
        for (int i = 0; i < 3; ++i)
            if (bval[i]) *(us8*)&Bs[b][bldso[i]] = vB[i];
    };

    LOADB(B1, 0);   // in flight during A staging

    // ---- stage A (128 x 320, once) ----
#pragma unroll
    for (int i = 0; i < 10; ++i) {
        int g = i * 512 + tid;        // 0..5119
        int row = g / 40, c = g - row * 40;
        int grow = bm + row; if (grow >= M) grow = M - 1;
        us8 v = *(const us8*)&Ap[(size_t)grow * PSTR + c * 8];
        *(us8*)&At[row * 320 + (c ^ (row & 7)) * 8] = v;
    }
    WRITEB(0);            // B1 step 0 -> Bs[0]
    LOADB(B1, 1);
    __syncthreads();      // At + Bs[0] visible

    f32x4 acc[4][5];

    // one barrier per step; compute(t) reads Bs[t&1] while Bs[(t+1)&1] fills
    auto RUN = [&](const unsigned short* B, const unsigned short* Bnext) {
        for (int t = 0; t < 10; ++t) {
            bf16x8 aS[4];
#pragma unroll
            for (int m = 0; m < 4; ++m) {
                int row = wm * 64 + m * 16 + lr;
                int c = t * 4 + lk;
                aS[m] = *(const bf16x8*)&At[row * 320 + (c ^ (row & 7)) * 8];
            }
#pragma unroll
            for (int n = 0; n < 5; ++n) {
                int rb = wn * 80 + n * 16 + lr;
                bf16x8 bh = *(const bf16x8*)&Bs[t & 1][rb * 32 + BSWZ(rb, lk) * 8];
#pragma unroll
                for (int m = 0; m < 4; ++m)
                    acc[m][n] = __builtin_amdgcn_mfma_f32_16x16x32_bf16(aS[m], bh, acc[m][n], 0, 0, 0);
            }
            if (t < 9) {
                WRITEB((t + 1) & 1);                 // vB holds step t+1
                if (t < 8) LOADB(B, t + 2);
                else if (Bnext) LOADB(Bnext, 0);     // prefetch next GEMM's step 0
            }
            __syncthreads();
        }
    };

    // ---- GEMM1 ----
#pragma unroll
    for (int m = 0; m < 4; ++m)
#pragma unroll
        for (int n = 0; n < 5; ++n) acc[m][n] = (f32x4)0.f;
    RUN(B1, B2);
    // after GEMM1: vB holds B2 step 0; final barrier done (At reads drained)

    // ---- T = relu(acc + b1) -> At ; stage B2 step 0 -> Bs[0] ----
#pragma unroll
    for (int n = 0; n < 5; ++n) {
        int col = wn * 80 + n * 16 + lr;
        int cc = col >> 3, cp = col & 7;
        float bv = b1v[n];
        bool vc = col < HID;
#pragma unroll
        for (int m = 0; m < 4; ++m) {
#pragma unroll
            for (int p = 0; p < 4; ++p) {
                int row = wm * 64 + m * 16 + lk * 4 + p;
                float v = vc ? fmaxf(acc[m][n][p] + bv, 0.f) : 0.f;
                At[row * 320 + ((cc ^ (row & 7)) * 8) + cp] = f2bf(v);
            }
        }
    }
    WRITEB(0);            // Bs[0] last read at t=8 (fenced by t=9 barrier)
    LOADB(B2, 1);
    __syncthreads();      // T + Bs[0] visible

    // ---- GEMM2 ----
#pragma unroll
    for (int m = 0; m < 4; ++m)
#pragma unroll
        for (int n = 0; n < 5; ++n) acc[m][n] = (f32x4)0.f;
    RUN(B2, nullptr);

    // ---- epilogue: act2(acc + b2) -> At -> coalesced stores ----
#pragma unroll
    for (int n = 0; n < 5; ++n) {
        int col = wn * 80 + n * 16 + lr;
        int cc = col >> 3, cp = col & 7;
        float bv = b2v[n];
        bool vc = col < HID;
#pragma unroll
        for (int m = 0; m < 4; ++m) {
#pragma unroll
            for (int p = 0; p < 4; ++p) {
                int row = wm * 64 + m * 16 + lk * 4 + p;
                float v = vc ? (acc[m][n][p] + bv) : 0.f;
                if (act2) v = fmaxf(v, 0.f);
                At[row * 320 + ((cc ^ (row & 7)) * 8) + cp] = f2bf(v);
            }
        }
    }
    __syncthreads();
#pragma unroll
    for (int i = 0; i < 10; ++i) {
        int g = i * 512 + tid;
        int row = g / 40, c = g - row * 40;
        int grow = bm + row;
        if (grow < M)
            *(us8*)&Op[(size_t)grow * PSTR + c * 8] =
                *(const us8*)&At[row * 320 + (c ^ (row & 7)) * 8];
    }
}

// ---------------------------------------------------------------- GEMM: fp32 A, 3-term split
// proj (outPlane=1: bf16 plane out, relu) and readout (outPlane=0: f32 out, prelu)
__global__ __launch_bounds__(256)
void gemm_f32A(const float* __restrict__ A, int lda, int M, int K, int KP,
               const unsigned short* __restrict__ BH, const unsigned short* __restrict__ BL, int KPB,
               const float* __restrict__ bias, int N,
               float* __restrict__ C, int ldc, unsigned short* __restrict__ Op, int outPlane,
               int act, const float* __restrict__ prelu) {
    __shared__ __align__(16) unsigned short AsH[64 * 40];
    __shared__ __align__(16) unsigned short AsL[64 * 40];
    __shared__ __align__(16) unsigned short BsH[320 * 40];
    __shared__ __align__(16) unsigned short BsL[320 * 40];

    const int tid = threadIdx.x;
    const int bm = blockIdx.y * 64;
    const int bn = blockIdx.x * 320;
    const int wid = tid >> 6, lane = tid & 63;
    const int lr = lane & 15, lk = lane >> 4;
    const int ar = tid >> 2, ac = tid & 3;

    f32x4 acc[4][5];
#pragma unroll
    for (int m = 0; m < 4; ++m)
#pragma unroll
        for (int n = 0; n < 5; ++n) acc[m][n] = (f32x4)0.f;

    for (int k0 = 0; k0 < KP; k0 += 32) {
        {
            int gm = bm + ar;
            int k = k0 + ac * 8;
            float v[8];
#pragma unroll
            for (int j = 0; j < 8; ++j) v[j] = 0.f;
            if (gm < M) {
                if (k + 7 < K) {
                    float4 p0 = *(const float4*)&A[(size_t)gm * lda + k];
                    float4 p1 = *(const float4*)&A[(size_t)gm * lda + k + 4];
                    v[0] = p0.x; v[1] = p0.y; v[2] = p0.z; v[3] = p0.w;
                    v[4] = p1.x; v[5] = p1.y; v[6] = p1.z; v[7] = p1.w;
                } else {
#pragma unroll
                    for (int j = 0; j < 8; ++j)
                        if (k + j < K) v[j] = A[(size_t)gm * lda + k + j];
                }
            }
            us8 h, l;
#pragma unroll
            for (int j = 0; j < 8; ++j) {
                unsigned short hb = f2bf(v[j]);
                h[j] = hb;
                l[j] = f2bf(v[j] - bf2f(hb));
            }
            *(us8*)&AsH[ar * 40 + ac * 8] = h;
            *(us8*)&AsL[ar * 40 + ac * 8] = l;
        }
#pragma unroll
        for (int p = 0; p < 5; ++p) {
            int r = ar + p * 64;
            size_t gb = (size_t)(bn + r) * KPB + k0 + ac * 8;
            *(us8*)&BsH[r * 40 + ac * 8] = *(const us8*)&BH[gb];
            *(us8*)&BsL[r * 40 + ac * 8] = *(const us8*)&BL[gb];
        }
        __syncthreads();
        bf16x8 aH[4], aL[4];
#pragma unroll
        for (int m = 0; m < 4; ++m) {
            aH[m] = *(const bf16x8*)&AsH[(m * 16 + lr) * 40 + lk * 8];
            aL[m] = *(const bf16x8*)&AsL[(m * 16 + lr) * 40 + lk * 8];
        }
#pragma unroll
        for (int n = 0; n < 5; ++n) {
            int r = wid * 80 + n * 16 + lr;
            bf16x8 bh = *(const bf16x8*)&BsH[r * 40 + lk * 8];
            bf16x8 bl = *(const bf16x8*)&BsL[r * 40 + lk * 8];
#pragma unroll
            for (int m = 0; m < 4; ++m) {
                acc[m][n] = __builtin_amdgcn_mfma_f32_16x16x32_bf16(aH[m], bh, acc[m][n], 0, 0, 0);
                acc[m][n] = __builtin_amdgcn_mfma_f32_16x16x32_bf16(aH[m], bl, acc[m][n], 0, 0, 0);
                acc[m][n] = __builtin_amdgcn_mfma_f32_16x16x32_bf16(aL[m], bh, acc[m][n], 0, 0, 0);
            }
        }
        __syncthreads();
    }
    float slope = (act == 2) ? prelu[0] : 0.f;
#pragma unroll
    for (int n = 0; n < 5; ++n) {
        int col = bn + wid * 80 + n * 16 + lr;
        bool vc = col < N;
        float bv = vc ? bias[col] : 0.f;
#pragma unroll
        for (int m = 0; m < 4; ++m) {
            int rbase = bm + m * 16 + lk * 4;
#pragma unroll
            for (int p = 0; p < 4; ++p) {
                int row = rbase + p;
                if (row >= M) continue;
                float v = vc ? (acc[m][n][p] + bv) : 0.f;
                if (act == 1) v = fmaxf(v, 0.f);
                else if (act == 2) v = (v >= 0.f) ? v : slope * v;
                if (outPlane) {
                    if (col < PSTR) Op[(size_t)row * PSTR + col] = f2bf(v);
                } else if (vc) {
                    C[(size_t)row * ldc + col] = v;
                }
            }
        }
    }
}

// ---------------------------------------------------------------- segmented pool (2 waves/graph)
__global__ __launch_bounds__(128)
void pool_seg(const unsigned short* __restrict__ h, const int* __restrict__ goffs,
              float* __restrict__ pooled) {
    __shared__ float red[6 * 64];
    int g = blockIdx.x;
    int w = threadIdx.x >> 6, lane = threadIdx.x & 63;
    int s = goffs[g], e = goffs[g + 1];
    float a0 = 0.f, a1 = 0.f, a2 = 0.f, a3 = 0.f, a4 = 0.f, a5 = 0.f;
    for (int node = s + w; node < e; node += 2) {
        const unsigned* r = (const unsigned*)(h + (size_t)node * PSTR);
        uint2 u = *(const uint2*)&r[2 * lane];
        unsigned t = (lane < 32) ? r[128 + lane] : 0u;
        a0 += bflo(u.x); a1 += bfhi(u.x);
        a2 += bflo(u.y); a3 += bfhi(u.y);
        a4 += bflo(t);   a5 += bfhi(t);
    }
    if (w == 1) {
        red[lane] = a0;        red[64 + lane] = a1;
        red[128 + lane] = a2;  red[192 + lane] = a3;
        red[256 + lane] = a4;  red[320 + lane] = a5;
    }
    __syncthreads();
    if (w == 0) {
        a0 += red[lane];        a1 += red[64 + lane];
        a2 += red[128 + lane];  a3 += red[192 + lane];
        a4 += red[256 + lane];  a5 += red[320 + lane];
        float* pr = pooled + (size_t)g * PSTR;
        *(float4*)&pr[4 * lane] = make_float4(a0, a1, a2, a3);
        if (lane < 32) *(float2*)&pr[256 + 2 * lane] = make_float2(a4, a5);
    }
}

// ---------------------------------------------------------------- launch
extern "C" void kernel_launch(void* const* d_in, const int* in_sizes, int n_in,
                              void* d_out, int out_size, void* d_ws, size_t ws_size,
                              hipStream_t stream) {
    const float* x      = (const float*)d_in[0];
    const int*   eidx   = (const int*)d_in[1];
    const int*   batch  = (const int*)d_in[2];
    const float* W_proj = (const float*)d_in[3];
    const float* b_proj = (const float*)d_in[4];
    const float* W1     = (const float*)d_in[5];
    const float* b1     = (const float*)d_in[6];
    const float* W2     = (const float*)d_in[7];
    const float* b2     = (const float*)d_in[8];
    const float* W_sp   = (const float*)d_in[9];
    const float* b_sp   = (const float*)d_in[10];
    const float* prelu  = (const float*)d_in[11];

    const int* src = eidx;
    const int* dst = eidx + N_EDGES;

    const size_t PLANE = (size_t)N_NODES * PSTR + 64;
    const int LAYER_SZ = 320 * 320;
    const int SP_SZ  = 1280 * 320;
    const int PJ_SZ  = 320 * 128;
    const int NB  = (N_NODES + 255) / 256;   // 196
    const int NBG = (N_GRAPHS + 255) / 256;  // 4

    unsigned short* hA  = (unsigned short*)d_ws;       // PLANE
    unsigned short* hB  = hA + PLANE;                  // PLANE
    float* pooled = (float*)(hB + PLANE);
    unsigned short* w1H = (unsigned short*)(pooled + (size_t)N_GRAPHS * PSTR + 16);
    unsigned short* w2H = w1H + 5 * (size_t)LAYER_SZ;
    unsigned short* spH = w2H + 5 * (size_t)LAYER_SZ;
    unsigned short* spL = spH + SP_SZ;
    unsigned short* pjH = spL + SP_SZ;
    unsigned short* pjL = pjH + PJ_SZ;
    int* cnt    = (int*)(((uintptr_t)(pjL + PJ_SZ) + 15) & ~(uintptr_t)15);
    int* gcnt   = cnt + N_NODES;
    int* bsum   = gcnt + N_GRAPHS;
    int* bbase  = bsum + 256;
    int* gsum   = bbase + 256;
    int* gbase  = gsum + 256;
    int* offs   = gbase + 256;
    int* goffs  = offs + N_NODES + 1;
    int* cursor = goffs + N_GRAPHS + 1;
    int* csr    = cursor + N_NODES;
    size_t needed = (size_t)((uintptr_t)(csr + N_EDGES) - (uintptr_t)d_ws);
    if (ws_size < needed) return;

    // ---- weight pre-split (one launch) ----
    split_all<<<dim3(40, 10, 12), 256, 0, stream>>>(W1, W2, W_sp, W_proj,
                                                    w1H, w2H, spH, spL, pjH, pjL);

    // ---- CSR + graph offsets (merged chains) ----
    hipMemsetAsync(cnt, 0, (N_NODES + N_GRAPHS) * sizeof(int), stream);
    hist2<<<(N_EDGES + N_NODES + 255) / 256, 256, 0, stream>>>(dst, cnt, batch, gcnt);
    scan_block2<<<NB + NBG, 256, 0, stream>>>(cnt, offs, bsum, gcnt, goffs, gsum, NB);
    scan_base2<<<2, 256, 0, stream>>>(bsum, bbase, NB, offs + N_NODES,
                                      gsum, gbase, NBG, goffs + N_GRAPHS);
    scan_add2<<<NB + NBG, 256, 0, stream>>>(offs, bbase, cursor, goffs, gbase, NB);
    scatter_kernel<<<(N_EDGES + 255) / 256, 256, 0, stream>>>(src, dst, cursor, csr, N_EDGES);

    // ---- projection: h0 = relu(x @ W_proj + b) -> hA (bf16 plane) ----
    gemm_f32A<<<dim3(1, (N_NODES + 63) / 64), 256, 0, stream>>>(
        x, NODE_IN, N_NODES, NODE_IN, 128, pjH, pjL, 128,
        b_proj, HID, nullptr, 0, hA, 1, 1, nullptr);

    // ---- GIN layers: agg (uint4 gather) + fused MLP (dbuf, 1 barrier/step) ----
    const int GBM = (N_NODES + 127) / 128;   // 391
    unsigned short* cur = hA;
    unsigned short* agp = hB;
    for (int i = 0; i < DEPTH; ++i) {
        aggregate_bf16<<<(N_NODES * 64 + 255) / 256, 256, 0, stream>>>(cur, offs, csr, agp);
        gin_mlp<<<GBM, 512, 0, stream>>>(
            agp, N_NODES,
            w1H + (size_t)i * LAYER_SZ, b1 + (size_t)i * HID,
            w2H + (size_t)i * LAYER_SZ, b2 + (size_t)i * HID,
            cur, (i < DEPTH - 1) ? 1 : 0);
    }

    // ---- segmented pool (batch sorted) ----
    pool_seg<<<N_GRAPHS, 128, 0, stream>>>(cur, goffs, pooled);

    // ---- readout: prelu(pooled @ W_sp + b_sp) ----
    gemm_f32A<<<dim3(4, (N_GRAPHS + 63) / 64), 256, 0, stream>>>(
        pooled, PSTR, N_GRAPHS, HID, 320, spH, spL, 320,
        b_sp, READOUT, (float*)d_out, READOUT, nullptr, 0, 2, prelu);
}